// Round 2
// baseline (110.023 us; speedup 1.0000x reference)
//
#include <hip/hip_runtime.h>

// Batched GEMM: C[b][i][j] = sum_d A[b][i][d] * B[b][j][d]
// B=16, M=N=1024, K=256, fp32 in/out, bf16 MFMA compute.

typedef __attribute__((ext_vector_type(8))) short bf16x8;
typedef __attribute__((ext_vector_type(4))) float f32x4;
typedef __attribute__((ext_vector_type(2))) unsigned int u32x2;

#define NBATCH 16
#define MDIM 1024
#define NDIM 1024
#define KDIM 256
#define BM 128
#define BN 128
#define BK 64

// round-half-up fp32->bf16 pair pack: one add per float + one v_perm per pair
__device__ __forceinline__ unsigned pack_bf2(float f0, float f1) {
  unsigned u0 = __builtin_bit_cast(unsigned, f0) + 0x8000u;
  unsigned u1 = __builtin_bit_cast(unsigned, f1) + 0x8000u;
  // result low16 = u0[31:16], high16 = u1[31:16]
  return __builtin_amdgcn_perm(u1, u0, 0x07060302u);
}

__global__ __launch_bounds__(256, 2) void batched_gemm_bt(
    const float* __restrict__ A, const float* __restrict__ B,
    float* __restrict__ C) {
  const int bid   = blockIdx.x;
  const int batch = bid >> 6;     // 64 tiles per batch (8x8)
  const int tile  = bid & 63;
  const int tm = tile >> 3, tn = tile & 7;

  const float* Ab = A + ((size_t)batch * MDIM + tm * BM) * KDIM;
  const float* Bb = B + ((size_t)batch * NDIM + tn * BN) * KDIM;
  float* Cb = C + (size_t)batch * MDIM * NDIM + (size_t)(tm * BM) * NDIM + tn * BN;

  // [buf][A/B][row*64 + swizzled-col]  (ushort units). 64 KiB total.
  // byte layout per row (128B): col_byte ^ ((row&7)<<4)  -> conflict-free b128 reads
  __shared__ ushort lds[2][2][BM * BK];

  const int tid  = threadIdx.x;
  const int lane = tid & 63;
  const int wid  = tid >> 6;
  const int wr = wid >> 1, wc = wid & 1;   // wave 2x2 grid, each 64x64 out

  // ---- staging mapping: thread -> (row = p*16 + tid/16, col4 = tid%16) ----
  const int srow = tid >> 4;   // 0..15
  const int scol = tid & 15;   // float4 index within row
  const float* ag = Ab + srow * KDIM + scol * 4;
  const float* bg = Bb + srow * KDIM + scol * 4;
  // LDS write offset (ushort units): row*64 + ((col4*4) ^ ((row&7)<<3)); row&7==srow&7
  const int widx0 = srow * 64 + (((scol * 4) ^ ((srow & 7) << 3)));

  // ---- fragment read offsets ----
  const int hi   = lane >> 4;          // k-group
  const int lrow = lane & 15;          // row within 16x16 frag
  const int xorm = (lane & 7) << 4;    // byte xor mask
  const int cofs0 = (((hi * 16)      ^ xorm) >> 1);  // ks=0, ushort units
  const int cofs1 = ((((hi * 16)+64) ^ xorm) >> 1);  // ks=1
  const int arow_base = (wr * 64 + lrow) * 64;
  const int brow_base = (wc * 64 + lrow) * 64;

  f32x4 ra[8], rb[8];
  f32x4 acc[4][4];
#pragma unroll
  for (int m = 0; m < 4; ++m)
#pragma unroll
    for (int n = 0; n < 4; ++n)
      acc[m][n] = (f32x4){0.f, 0.f, 0.f, 0.f};

#define LOADS(kt)                                                        \
  do {                                                                   \
    _Pragma("unroll") for (int p = 0; p < 8; ++p) {                      \
      ra[p] = *(const f32x4*)(ag + (kt) * BK + p * 16 * KDIM);           \
      rb[p] = *(const f32x4*)(bg + (kt) * BK + p * 16 * KDIM);           \
    }                                                                    \
  } while (0)

#define WRITES(bufi)                                                     \
  do {                                                                   \
    _Pragma("unroll") for (int p = 0; p < 8; ++p) {                      \
      u32x2 wa, wb;                                                      \
      wa[0] = pack_bf2(ra[p][0], ra[p][1]);                              \
      wa[1] = pack_bf2(ra[p][2], ra[p][3]);                              \
      wb[0] = pack_bf2(rb[p][0], rb[p][1]);                              \
      wb[1] = pack_bf2(rb[p][2], rb[p][3]);                              \
      *(u32x2*)(&lds[bufi][0][widx0 + p * 1024]) = wa;                   \
      *(u32x2*)(&lds[bufi][1][widx0 + p * 1024]) = wb;                   \
    }                                                                    \
  } while (0)

#define COMPUTE(bufi)                                                    \
  do {                                                                   \
    const ushort* la = &lds[bufi][0][0];                                 \
    const ushort* lb = &lds[bufi][1][0];                                 \
    _Pragma("unroll") for (int ks = 0; ks < 2; ++ks) {                   \
      const int cofs = ks ? cofs1 : cofs0;                               \
      bf16x8 af[4], bfr[4];                                              \
      _Pragma("unroll") for (int m = 0; m < 4; ++m)                      \
        af[m] = *(const bf16x8*)(la + arow_base + m * 16 * 64 + cofs);   \
      _Pragma("unroll") for (int n = 0; n < 4; ++n)                      \
        bfr[n] = *(const bf16x8*)(lb + brow_base + n * 16 * 64 + cofs);  \
      _Pragma("unroll") for (int m = 0; m < 4; ++m)                      \
        _Pragma("unroll") for (int n = 0; n < 4; ++n)                    \
          acc[m][n] = __builtin_amdgcn_mfma_f32_16x16x32_bf16(           \
              af[m], bfr[n], acc[m][n], 0, 0, 0);                        \
    }                                                                    \
  } while (0)

  // K = 256 -> 4 steps of BK=64, double-buffered, loads issued ahead of compute
  LOADS(0);
  WRITES(0);
  __syncthreads();

  LOADS(1);
  COMPUTE(0);
  WRITES(1);
  __syncthreads();

  LOADS(2);
  COMPUTE(1);
  WRITES(0);
  __syncthreads();

  LOADS(3);
  COMPUTE(0);
  WRITES(1);
  __syncthreads();

  COMPUTE(1);

#undef LOADS
#undef WRITES
#undef COMPUTE

  // C/D layout: col = lane&15, row = (lane>>4)*4 + reg   (m89-verified)
  float* cw = Cb + (size_t)(wr * 64 + hi * 4) * NDIM + wc * 64 + lrow;
#pragma unroll
  for (int m = 0; m < 4; ++m)
#pragma unroll
    for (int n = 0; n < 4; ++n)
#pragma unroll
      for (int j = 0; j < 4; ++j)
        cw[(size_t)(m * 16 + j) * NDIM + n * 16] = acc[m][n][j];
}

extern "C" void kernel_launch(void* const* d_in, const int* in_sizes, int n_in,
                              void* d_out, int out_size, void* d_ws, size_t ws_size,
                              hipStream_t stream) {
  const float* A = (const float*)d_in[0];
  const float* B = (const float*)d_in[1];
  float* C = (float*)d_out;
  batched_gemm_bt<<<dim3(NBATCH * 8 * 8), dim3(256), 0, stream>>>(A, B, C);
}

// Round 3
// 103.570 us; speedup vs baseline: 1.0623x; 1.0623x over previous
//
#include <hip/hip_runtime.h>

// Batched GEMM: C[b][i][j] = sum_d A[b][i][d] * B[b][j][d]
// B=16, M=N=1024, K=256, fp32 in/out, bf16 MFMA compute.
// R3: BK=32 + padded LDS rows (40KB -> 4 blocks/CU, grid fully resident),
//     XCD chunk swizzle (each XCD's L2 holds exactly 2 batches' inputs).

typedef __attribute__((ext_vector_type(8))) short bf16x8;
typedef __attribute__((ext_vector_type(4))) float f32x4;
typedef __attribute__((ext_vector_type(2))) unsigned int u32x2;

#define NBATCH 16
#define MDIM 1024
#define NDIM 1024
#define KDIM 256
#define BM 128
#define BN 128
#define BK 32
#define ROWP 40  // row stride in ushorts (80B = 64B data + 16B pad -> <=2-way banks)

// round-half-up fp32->bf16 pair pack
__device__ __forceinline__ unsigned pack_bf2(float f0, float f1) {
  unsigned u0 = __builtin_bit_cast(unsigned, f0) + 0x8000u;
  unsigned u1 = __builtin_bit_cast(unsigned, f1) + 0x8000u;
  return __builtin_amdgcn_perm(u1, u0, 0x07060302u);  // lo16=u0.hi, hi16=u1.hi
}

__global__ __launch_bounds__(256, 4) void batched_gemm_bt(
    const float* __restrict__ A, const float* __restrict__ B,
    float* __restrict__ C) {
  // XCD chunk swizzle: hardware assigns XCD = bid%8; remap so XCD x runs
  // blocks [x*128, (x+1)*128) = batches {2x, 2x+1} -> 4MB working set = L2.
  const int bid = blockIdx.x;
  const int nb  = ((bid & 7) << 7) | (bid >> 3);
  const int batch = nb >> 6;  // 64 tiles (8x8) per batch
  const int tile  = nb & 63;
  const int tm = tile >> 3, tn = tile & 7;

  const float* Ab = A + ((size_t)batch * MDIM + tm * BM) * KDIM;
  const float* Bb = B + ((size_t)batch * NDIM + tn * BN) * KDIM;
  float* Cb = C + (size_t)batch * MDIM * NDIM + (size_t)(tm * BM) * NDIM + tn * BN;

  __shared__ ushort lds[2][2][BM * ROWP];  // [buf][A/B][row*ROWP + col] = 40 KiB

  const int tid  = threadIdx.x;
  const int lane = tid & 63;
  const int wid  = tid >> 6;
  const int wr = wid >> 1, wc = wid & 1;  // wave 2x2 grid, each 64x64 out

  // staging: thread -> (row = p*32 + tid/8, float4-col = tid%8)
  const int srow = tid >> 3;  // 0..31
  const int scol = tid & 7;   // float4 index within 32-float row
  const float* ag = Ab + srow * KDIM + scol * 4;
  const float* bg = Bb + srow * KDIM + scol * 4;
  const int widx0 = srow * ROWP + scol * 4;  // ushort units

  // fragment read offsets: lane reads row (l&15), k-bytes [hi*16, hi*16+16)
  const int hi   = lane >> 4;
  const int lrow = lane & 15;
  const int aofs = (wr * 64 + lrow) * ROWP + hi * 8;  // ushort units
  const int bofs = (wc * 64 + lrow) * ROWP + hi * 8;

  f32x4 ra[4], rb[4];
  f32x4 acc[4][4];
#pragma unroll
  for (int m = 0; m < 4; ++m)
#pragma unroll
    for (int n = 0; n < 4; ++n)
      acc[m][n] = (f32x4){0.f, 0.f, 0.f, 0.f};

#define LOADS(kt)                                                       \
  do {                                                                  \
    _Pragma("unroll") for (int p = 0; p < 4; ++p) {                     \
      ra[p] = *(const f32x4*)(ag + (kt) * BK + p * 32 * KDIM);          \
      rb[p] = *(const f32x4*)(bg + (kt) * BK + p * 32 * KDIM);          \
    }                                                                   \
  } while (0)

#define WRITES(bufi)                                                    \
  do {                                                                  \
    _Pragma("unroll") for (int p = 0; p < 4; ++p) {                     \
      u32x2 wa, wb;                                                     \
      wa[0] = pack_bf2(ra[p][0], ra[p][1]);                             \
      wa[1] = pack_bf2(ra[p][2], ra[p][3]);                             \
      wb[0] = pack_bf2(rb[p][0], rb[p][1]);                             \
      wb[1] = pack_bf2(rb[p][2], rb[p][3]);                             \
      *(u32x2*)(&lds[bufi][0][widx0 + p * 32 * ROWP]) = wa;             \
      *(u32x2*)(&lds[bufi][1][widx0 + p * 32 * ROWP]) = wb;             \
    }                                                                   \
  } while (0)

#define COMPUTE(bufi)                                                   \
  do {                                                                  \
    const ushort* la = &lds[bufi][0][0];                                \
    const ushort* lb = &lds[bufi][1][0];                                \
    bf16x8 af[4], bfr[4];                                               \
    _Pragma("unroll") for (int m = 0; m < 4; ++m)                       \
      af[m] = *(const bf16x8*)(la + aofs + m * 16 * ROWP);              \
    _Pragma("unroll") for (int n = 0; n < 4; ++n)                       \
      bfr[n] = *(const bf16x8*)(lb + bofs + n * 16 * ROWP);             \
    _Pragma("unroll") for (int m = 0; m < 4; ++m)                       \
      _Pragma("unroll") for (int n = 0; n < 4; ++n)                     \
        acc[m][n] = __builtin_amdgcn_mfma_f32_16x16x32_bf16(            \
            af[m], bfr[n], acc[m][n], 0, 0, 0);                         \
  } while (0)

  // K = 256 -> 8 steps of BK=32, rotating double buffer, loads one step ahead
  LOADS(0);
  WRITES(0);
  __syncthreads();
#pragma unroll
  for (int k = 0; k < 7; ++k) {
    LOADS(k + 1);
    COMPUTE(k & 1);
    WRITES((k + 1) & 1);
    __syncthreads();
  }
  COMPUTE(1);  // kt=7 lives in buf 1

#undef LOADS
#undef WRITES
#undef COMPUTE

  // C/D layout: col = lane&15, row = (lane>>4)*4 + reg (m89-verified)
  float* cw = Cb + (size_t)(wr * 64 + hi * 4) * NDIM + wc * 64 + lrow;
#pragma unroll
  for (int m = 0; m < 4; ++m)
#pragma unroll
    for (int n = 0; n < 4; ++n)
#pragma unroll
      for (int j = 0; j < 4; ++j)
        cw[(size_t)(m * 16 + j) * NDIM + n * 16] = acc[m][n][j];
}

extern "C" void kernel_launch(void* const* d_in, const int* in_sizes, int n_in,
                              void* d_out, int out_size, void* d_ws, size_t ws_size,
                              hipStream_t stream) {
  const float* A = (const float*)d_in[0];
  const float* B = (const float*)d_in[1];
  float* C = (float*)d_out;
  batched_gemm_bt<<<dim3(NBATCH * 8 * 8), dim3(256), 0, stream>>>(A, B, C);
}